// Round 16
// baseline (198.101 us; speedup 1.0000x reference)
//
#include <hip/hip_runtime.h>

typedef unsigned short u16;
typedef __bf16 bf16_t;
typedef bf16_t bf16x8 __attribute__((ext_vector_type(8)));
typedef float f32x4 __attribute__((ext_vector_type(4)));
typedef float f32x16 __attribute__((ext_vector_type(16)));
typedef u16 u16x8 __attribute__((ext_vector_type(8)));
typedef u16 u16x4 __attribute__((ext_vector_type(4)));

#define DEV static __device__ __forceinline__

// ---- constants ----
#define BATCH 2
#define SEQ 2048
#define DM 1024
#define NH 16
#define DH 64
#define NTOK 4096            // BATCH*SEQ
#define ATT_SCALE 0.125f     // 1/sqrt(64)

DEV float bf2f(u16 x) { union { unsigned u; float f; } v; v.u = ((unsigned)x) << 16; return v.f; }
DEV u16 f2bf(float x) {
    union { float f; unsigned u; } v; v.f = x;
    unsigned u = v.u;
    return (u16)((u + 0x7fffu + ((u >> 16) & 1u)) >> 16);
}
DEV f32x4 mfma16(bf16x8 a, bf16x8 b, f32x4 c) {
    return __builtin_amdgcn_mfma_f32_16x16x32_bf16(a, b, c, 0, 0, 0);
}
DEV f32x16 mfma32(bf16x8 a, bf16x8 b, f32x16 c) {
    return __builtin_amdgcn_mfma_f32_32x32x16_bf16(a, b, c, 0, 0, 0);
}
DEV f32x4 zero4() { f32x4 z; z[0] = 0.f; z[1] = 0.f; z[2] = 0.f; z[3] = 0.f; return z; }
DEV f32x16 zero16() {
    f32x16 z;
    #pragma unroll
    for (int i = 0; i < 16; i++) z[i] = 0.f;
    return z;
}

// async global->LDS, 16B per lane.  LDS dest is wave-uniform base + lane*16.
DEV void gl16(const u16* g, u16* l) {
    __builtin_amdgcn_global_load_lds(
        (const __attribute__((address_space(1))) unsigned int*)g,
        (__attribute__((address_space(3))) unsigned int*)l,
        16, 0, 0);
}

// =====================================================================
// Kernel 0: PREP — fused weight transpose (z<4) + x fp32->bf16 (z>=4).
// grid (16, 16, 20), block 256.
// =====================================================================
__global__ __launch_bounds__(256) void prep(
    const float* __restrict__ x, u16* __restrict__ xb,
    const float* __restrict__ W0, const float* __restrict__ W1,
    const float* __restrict__ W2, const float* __restrict__ W3,
    u16* __restrict__ T0, u16* __restrict__ T1,
    u16* __restrict__ T2, u16* __restrict__ T3)
{
    __shared__ u16 tile[64][65];
    const int z = blockIdx.z;
    const int tid = threadIdx.x;

    if (z >= 4) {
        int bid = (z - 4) * 256 + blockIdx.y * 16 + blockIdx.x;
        int i = (bid * 256 + tid) * 4;
        f32x4 v = *(const f32x4*)(x + i);
        u16x4 o;
        #pragma unroll
        for (int j = 0; j < 4; j++) o[j] = f2bf(v[j]);
        *(u16x4*)(xb + i) = o;
        return;
    }

    const float* W; u16* T;
    switch (z) {
        case 0:  W = W0; T = T0; break;
        case 1:  W = W1; T = T1; break;
        case 2:  W = W2; T = T2; break;
        default: W = W3; T = T3; break;
    }
    const int o0 = blockIdx.x * 64;
    const int k0 = blockIdx.y * 64;
    #pragma unroll
    for (int v = 0; v < 4; v++) {
        int idx = (tid + v * 256) * 4;
        int r = idx >> 6, c = idx & 63;           // r: k offset, c: o offset
        f32x4 d = *(const f32x4*)(W + (size_t)(k0 + r) * DM + o0 + c);
        #pragma unroll
        for (int j = 0; j < 4; j++) tile[r][c + j] = f2bf(d[j]);
    }
    __syncthreads();
    #pragma unroll
    for (int v = 0; v < 2; v++) {
        int idx = (tid + v * 256) * 8;
        int r = idx >> 6, c = idx & 63;           // r: o offset, c: k offset
        u16x8 d;
        #pragma unroll
        for (int j = 0; j < 8; j++) d[j] = tile[c + j][r];
        *(u16x8*)(T + (size_t)(o0 + r) * DM + k0 + c) = d;
    }
}

// =====================================================================
// Kernel 2: FUSED QKV projection, t-tile 64 (was 128): grid (16,64) =
// 1024 blocks = 4 blocks/CU (was 2 — grid-limited).  One block = 64
// t-rows x 64 o-cols for ALL THREE matrices (A staged once, reused 3x).
// LDS 32 KB: A 8KB + 3x8KB B.  4 waves (2x2): wave = 32m x 32n,
// acc[3][2][2].  XCD swizzle on o-tile.  BK=64, gl16, XOR chunk swizzle.
// =====================================================================
__global__ __launch_bounds__(256) void qkv_gemm(
    const u16* __restrict__ X, const u16* __restrict__ WT0,
    const float* __restrict__ bq, const float* __restrict__ bk, const float* __restrict__ bv,
    u16* __restrict__ qws, u16* __restrict__ kws, u16* __restrict__ vws)
{
    __shared__ __attribute__((aligned(16))) u16 smem[16384];  // 32 KB
    u16* As = smem;           // 64x64
    u16* Bs = smem + 4096;    // 3 x (64x64)

    const int n  = blockIdx.x + 16 * blockIdx.y;        // 0..1023, XCD = n%8
    const int ot = (n & 7) | (((n >> 9) & 1) << 3);     // o-tile 0..15
    const int tt = (n >> 3) & 63;                       // t-tile 0..63
    const int o0 = ot * 64;
    const int t0 = tt * 64;
    const int tid  = threadIdx.x;
    const int wave = tid >> 6;
    const int lane = tid & 63;
    const int q = lane >> 4;
    const int c = lane & 15;
    const int wm = wave >> 1, wn = wave & 1;

    // staging lane constants: row_off = lane>>3, swizzled global chunk
    const int cswz = (((lane & 7) ^ ((lane >> 3) & 7)) * 8);
    const u16* gA = X + (size_t)(t0 + wave * 16 + (lane >> 3)) * DM + cswz;
    const u16* gB = WT0 + (size_t)(o0 + wave * 16 + (lane >> 3)) * DM + cswz;

    f32x4 acc[3][2][2];
    #pragma unroll
    for (int m = 0; m < 3; m++)
        #pragma unroll
        for (int mt = 0; mt < 2; mt++)
            #pragma unroll
            for (int nt = 0; nt < 2; nt++) acc[m][mt][nt] = zero4();

    for (int kt = 0; kt < DM / 64; kt++) {
        __syncthreads();
        #pragma unroll
        for (int i = 0; i < 2; i++)
            gl16(gA + (size_t)i * 8 * DM + kt * 64, As + (wave * 2 + i) * 512);
        #pragma unroll
        for (int m = 0; m < 3; m++)
            #pragma unroll
            for (int i = 0; i < 2; i++)
                gl16(gB + (size_t)m * (1u << 20) + (size_t)i * 8 * DM + kt * 64,
                     Bs + m * 4096 + (wave * 2 + i) * 512);
        __syncthreads();
        #pragma unroll
        for (int ks = 0; ks < 2; ks++) {
            const int cc = ((ks * 4 + q) ^ (c & 7)) * 8;
            bf16x8 a[2];
            #pragma unroll
            for (int mt = 0; mt < 2; mt++)
                a[mt] = *(const bf16x8*)&As[(wm * 32 + mt * 16 + c) * 64 + cc];
            #pragma unroll
            for (int m = 0; m < 3; m++) {
                bf16x8 b[2];
                #pragma unroll
                for (int nt = 0; nt < 2; nt++)
                    b[nt] = *(const bf16x8*)&Bs[m * 4096 + (wn * 32 + nt * 16 + c) * 64 + cc];
                #pragma unroll
                for (int mt = 0; mt < 2; mt++)
                    #pragma unroll
                    for (int nt = 0; nt < 2; nt++)
                        acc[m][mt][nt] = mfma16(a[mt], b[nt], acc[m][mt][nt]);
            }
        }
    }

    // ---- Q, K epilogue: direct scatter to (b,h,s,dh) ----
    #pragma unroll
    for (int m = 0; m < 2; m++) {
        u16* dst = (m == 0) ? qws : kws;
        const float* bias = (m == 0) ? bq : bk;
        #pragma unroll
        for (int mt = 0; mt < 2; mt++)
            #pragma unroll
            for (int nt = 0; nt < 2; nt++)
                #pragma unroll
                for (int r = 0; r < 4; r++) {
                    int mm = wm * 32 + mt * 16 + q * 4 + r;
                    int n2 = wn * 32 + nt * 16 + c;
                    int t = t0 + mm, o = o0 + n2;
                    float val = acc[m][mt][nt][r] + bias[o];
                    int b  = t >> 11, s = t & 2047;
                    int h  = o >> 6,  dh = o & 63;
                    dst[(((size_t)(b * NH + h)) * SEQ + s) * DH + dh] = f2bf(val);
                }
    }

    // ---- V epilogue: transpose through LDS -> coalesced (b,h,dh,s) ----
    __syncthreads();                       // As/Bs reads complete
    #pragma unroll
    for (int mt = 0; mt < 2; mt++)
        #pragma unroll
        for (int nt = 0; nt < 2; nt++) {
            int n_l = wn * 32 + nt * 16 + c;       // 0..63 (dh)
            int m_l = wm * 32 + mt * 16 + q * 4;   // 0..63 (t row)
            float bi = bv[o0 + n_l];
            u16x4 pk;
            #pragma unroll
            for (int r = 0; r < 4; r++) pk[r] = f2bf(acc[2][mt][nt][r] + bi);
            *(u16x4*)&smem[n_l * 72 + m_l] = pk;
        }
    __syncthreads();
    const int h = o0 >> 6;                 // one head per 64-wide n-tile
    #pragma unroll
    for (int v = 0; v < 2; v++) {
        int idx   = tid + v * 256;         // 0..511
        int o_l   = idx >> 3;              // 0..63 (dh)
        int chunk = idx & 7;               // 0..7
        int t_l   = chunk * 8;
        u16x8 d = *(const u16x8*)&smem[o_l * 72 + t_l];
        int t = t0 + t_l;
        int b = t >> 11, s = t & 2047;
        *(u16x8*)&vws[(((size_t)(b * NH + h)) * DH + o_l) * SEQ + s] = d;
    }
}

// =====================================================================
// Kernel 3: flash attention (R14 form — best measured, 52.2us steady).
// 32x32 swapped-QK^T, register-resident P, SPLIT-K + LDS staging +
// XCD head binding + padded LDS via 9x gl16 ([64][72], zero-conflict).
// Block = 64 q-rows, 4 waves (qg,kg); wave (qg,kg): q-rows qg*32..,
// key tiles 2*it+kg.  Partial O,l combined through LDS at the end.
// grid (32,32) = 1024 blocks = 4 blocks/CU.
// =====================================================================
__global__ __launch_bounds__(256, 4) void attn_kernel(
    const u16* __restrict__ qws, const u16* __restrict__ kws,
    const u16* __restrict__ vws, u16* __restrict__ aout)
{
    // u16 units: K tiles [2][64][72] at [0,9216); V tiles at [9216,18432)
    // epilogue alias: Ox [128][36] f32 + Lp[64] + Linv[64] (18.9 KB)
    __shared__ __attribute__((aligned(16))) u16 smem[18432];

    const int n   = blockIdx.x + 32 * blockIdx.y;   // launch id, XCD = n%8
    const int qt  = (n >> 3) & 31;
    const int bh  = (n & 7) | ((n >> 8) << 3);
    const int tid  = threadIdx.x;
    const int wave = tid >> 6;
    const int lane = tid & 63;
    const int c32 = lane & 31;
    const int hi  = lane >> 5;
    const int qg  = wave >> 1;         // q-group (0,1)
    const int kg  = wave & 1;          // key-half (0,1)

    const u16* Qh  = qws + (size_t)bh * SEQ * DH;
    const u16* Kh  = kws + (size_t)bh * SEQ * DH;
    const u16* Vth = vws + (size_t)bh * DH * SEQ;

    const int s0 = qt * 64 + qg * 32;  // wave's q rows

    // ---- staging role: wave stages one [64][72] tile with 9 gl16 ----
    const bool isK = (wave < 2);
    const int  sg  = wave & 1;
    u16* dstT = smem + (isK ? 0 : 9216) + sg * 4608;
    const u16* baseT = isK ? (Kh + (size_t)sg * 64 * DH) : (Vth + sg * 64);
    const size_t itStride = isK ? (size_t)(128 * DH) : (size_t)128;
    int toff[9];
    #pragma unroll
    for (int k = 0; k < 9; k++) {
        int p = 64 * k + lane;          // 16-B position in [0,576)
        int row = p / 9;
        int slot = p - 9 * row;
        int cs = (slot == 8) ? 0 : slot * 8;   // pad slot: duplicate slot 0
        toff[k] = isK ? (row * DH + cs) : (row * SEQ + cs);
    }

    // compute-side buffers (own key-half), padded stride 72
    const u16* KSg = smem + kg * 4608;
    const u16* VSg = smem + 9216 + kg * 4608;

    // Q^T B-fragments: lane holds Q[s0+c32][st*16 + hi*8 + j], pre-scaled
    bf16x8 qf[4];
    #pragma unroll
    for (int st = 0; st < 4; st++) {
        u16x8 raw = *(const u16x8*)(Qh + (size_t)(s0 + c32) * DH + st * 16 + hi * 8);
        u16x8 sv;
        #pragma unroll
        for (int j = 0; j < 8; j++) sv[j] = f2bf(bf2f(raw[j]) * ATT_SCALE);
        qf[st] = *(bf16x8*)&sv;
    }

    float lacc = 0.f;
    f32x16 o_acc[2];
    o_acc[0] = zero16();
    o_acc[1] = zero16();

    for (int it = 0; it < 16; ++it) {
        // stage this iteration's tile (keys [it*128, it*128+128))
        const u16* sb = baseT + (size_t)it * itStride;
        #pragma unroll
        for (int k = 0; k < 9; k++)
            gl16(sb + toff[k], dstT + k * 512);
        __syncthreads();   // vmcnt drained by compiler before barrier

        // S^T = K @ Q^T for own tile; exp+pack per 32-key block.
        // d[kb][s][i]: keys kb*32 + 8s + 4hi + 2i + {0,1}, qrow = c32
        unsigned d[2][4][2];
        #pragma unroll
        for (int kb = 0; kb < 2; kb++) {
            f32x16 sta = zero16();
            #pragma unroll
            for (int st = 0; st < 4; st++) {
                bf16x8 kfv = *(const bf16x8*)&KSg[(kb * 32 + c32) * 72
                                                  + (st * 2 + hi) * 8];
                sta = mfma32(kfv, qf[st], sta);
            }
            #pragma unroll
            for (int s = 0; s < 4; s++) {
                float p0 = __expf(sta[4 * s + 0]);
                float p1 = __expf(sta[4 * s + 1]);
                float p2 = __expf(sta[4 * s + 2]);
                float p3 = __expf(sta[4 * s + 3]);
                lacc += (p0 + p1) + (p2 + p3);
                asm("v_cvt_pk_bf16_f32 %0, %1, %2" : "=v"(d[kb][s][0]) : "v"(p0), "v"(p1));
                asm("v_cvt_pk_bf16_f32 %0, %1, %2" : "=v"(d[kb][s][1]) : "v"(p2), "v"(p3));
            }
        }

        // O += P @ V.  permlane32_swap on the d-pair gives pf =
        // {a0,a1,b0,b1} for ALL lanes directly (no cndmask).
        #pragma unroll
        for (int stv = 0; stv < 4; stv++) {
            const int kb = stv >> 1;
            const int m2 = (stv & 1) * 2;
            unsigned a0 = d[kb][m2][0],     a1 = d[kb][m2][1];
            unsigned b0 = d[kb][m2 + 1][0], b1 = d[kb][m2 + 1][1];
            asm("v_permlane32_swap_b32 %0, %1" : "+v"(a0), "+v"(b0));
            asm("v_permlane32_swap_b32 %0, %1" : "+v"(a1), "+v"(b1));
            union { unsigned u[4]; bf16x8 v; } pf;
            pf.u[0] = a0; pf.u[1] = a1; pf.u[2] = b0; pf.u[3] = b1;
            #pragma unroll
            for (int dhb = 0; dhb < 2; dhb++) {
                bf16x8 vf = *(const bf16x8*)&VSg[(dhb * 32 + c32) * 72
                                                 + (stv * 2 + hi) * 8];
                o_acc[dhb] = mfma32(pf.v, vf, o_acc[dhb]);
            }
        }
        __syncthreads();   // all waves done reading before next staging
    }

    // ---- split-K combine through LDS ----
    float lt = lacc;
    lt += __shfl_xor(lt, 32, 64);

    float* Ox   = (float*)smem;            // [128][36] (stride 36: 2-way free)
    float* Lp   = (float*)smem + 4608;     // [64]
    float* Linv = (float*)smem + 4672;     // [64]

    if (kg == 1) {
        const int xr = qg * 64 + lane;
        #pragma unroll
        for (int dhb = 0; dhb < 2; dhb++)
            #pragma unroll
            for (int s = 0; s < 4; s++) {
                f32x4 t;
                t[0] = o_acc[dhb][s * 4 + 0]; t[1] = o_acc[dhb][s * 4 + 1];
                t[2] = o_acc[dhb][s * 4 + 2]; t[3] = o_acc[dhb][s * 4 + 3];
                *(f32x4*)&Ox[xr * 36 + dhb * 16 + s * 4] = t;
            }
        if (hi == 0) Lp[qg * 32 + c32] = lt;
    }
    __syncthreads();
    if (kg == 0) {
        float inv = 1.0f / (lt + Lp[qg * 32 + c32]);
        if (hi == 0) Linv[qg * 32 + c32] = inv;
    }
    __syncthreads();
    if (kg == 0) {
        const int xr = qg * 64 + lane;
        #pragma unroll
        for (int dhb = 0; dhb < 2; dhb++)
            #pragma unroll
            for (int s = 0; s < 4; s++) {
                f32x4 pp = *(const f32x4*)&Ox[xr * 36 + dhb * 16 + s * 4];
                #pragma unroll
                for (int r = 0; r < 4; r++) o_acc[dhb][s * 4 + r] += pp[r];
            }
        const int b = bh >> 4, h = bh & 15;
        #pragma unroll
        for (int s = 0; s < 4; s++) {
            f32x4 iv = *(const f32x4*)&Linv[qg * 32 + s * 8 + hi * 4];
            #pragma unroll
            for (int r = 0; r < 4; r++) {
                int srow = s0 + s * 8 + hi * 4 + r;   // row = (reg&3)+8(reg>>2)+4hi
                size_t t = (size_t)b * SEQ + srow;
                #pragma unroll
                for (int dhb = 0; dhb < 2; dhb++) {
                    int ch = h * DH + dhb * 32 + c32;
                    aout[t * DM + ch] = f2bf(o_acc[dhb][s * 4 + r] * iv[r]);
                }
            }
        }
    }
}

// =====================================================================
// Kernel 4: output projection, 128x64 tile, fp32 output + XCD swizzle.
// grid (16, 32) = 512 blocks, block 256.
// =====================================================================
__global__ __launch_bounds__(256, 4) void out_gemm(
    const u16* __restrict__ A,  const u16* __restrict__ WT,
    const float* __restrict__ bias, float* __restrict__ out)
{
    __shared__ __attribute__((aligned(16))) u16 smem[12288];
    u16* As = smem;
    u16* Bs = smem + 8192;

    const int n  = blockIdx.x + 16 * blockIdx.y;        // 0..511, XCD = n%8
    const int ot = (n & 7) | (((n >> 8) & 1) << 3);     // o-tile 0..15
    const int tt = (n >> 3) & 31;                       // t-tile 0..31
    const int o0 = ot * 64;
    const int t0 = tt * 128;
    const int tid  = threadIdx.x;
    const int wave = tid >> 6;
    const int lane = tid & 63;
    const int q = lane >> 4;
    const int c = lane & 15;
    const int wm = wave >> 1, wn = wave & 1;

    const int cswz = (((lane & 7) ^ ((lane >> 3) & 7)) * 8);
    const u16* gA = A  + (size_t)(t0 + wave * 32 + (lane >> 3)) * DM + cswz;
    const u16* gB = WT + (size_t)(o0 + wave * 16 + (lane >> 3)) * DM + cswz;

    f32x4 acc[4][2];
    #pragma unroll
    for (int mt = 0; mt < 4; mt++)
        #pragma unroll
        for (int nt = 0; nt < 2; nt++) acc[mt][nt] = zero4();

    for (int kt = 0; kt < DM / 64; kt++) {
        __syncthreads();
        #pragma unroll
        for (int i = 0; i < 4; i++)
            gl16(gA + (size_t)i * 8 * DM + kt * 64, As + (wave * 4 + i) * 512);
        #pragma unroll
        for (int i = 0; i < 2; i++)
            gl16(gB + (size_t)i * 8 * DM + kt * 64, Bs + (wave * 2 + i) * 512);
        __syncthreads();
        #pragma unroll
        for (int ks = 0; ks < 2; ks++) {
            const int cc = ((ks * 4 + q) ^ (c & 7)) * 8;
            bf16x8 a[4], b[2];
            #pragma unroll
            for (int mt = 0; mt < 4; mt++)
                a[mt] = *(const bf16x8*)&As[(wm * 64 + mt * 16 + c) * 64 + cc];
            #pragma unroll
            for (int nt = 0; nt < 2; nt++)
                b[nt] = *(const bf16x8*)&Bs[(wn * 32 + nt * 16 + c) * 64 + cc];
            #pragma unroll
            for (int mt = 0; mt < 4; mt++)
                #pragma unroll
                for (int nt = 0; nt < 2; nt++)
                    acc[mt][nt] = mfma16(a[mt], b[nt], acc[mt][nt]);
        }
    }

    #pragma unroll
    for (int mt = 0; mt < 4; mt++)
        #pragma unroll
        for (int nt = 0; nt < 2; nt++)
            #pragma unroll
            for (int r = 0; r < 4; r++) {
                int m = wm * 64 + mt * 16 + q * 4 + r;
                int n2 = wn * 32 + nt * 16 + c;
                size_t t = t0 + m;
                int o = o0 + n2;
                out[t * DM + o] = acc[mt][nt][r] + bias[o];
            }
}

// =====================================================================
extern "C" void kernel_launch(void* const* d_in, const int* in_sizes, int n_in,
                              void* d_out, int out_size, void* d_ws, size_t ws_size,
                              hipStream_t stream)
{
    const float* x  = (const float*)d_in[0];
    const float* Wq = (const float*)d_in[1];
    const float* bq = (const float*)d_in[2];
    const float* Wk = (const float*)d_in[3];
    const float* bk = (const float*)d_in[4];
    const float* Wv = (const float*)d_in[5];
    const float* bv = (const float*)d_in[6];
    const float* Wo = (const float*)d_in[7];
    const float* bo = (const float*)d_in[8];
    float* out = (float*)d_out;

    // workspace carve (bf16 elements): 20M elems = 40 MB
    u16* ws   = (u16*)d_ws;
    u16* qws  = ws;                              // 4M elems
    u16* kws  = ws + (size_t)(4u << 20);         // 4M
    u16* vws  = ws + (size_t)(8u << 20);         // 4M (transposed per-head)
    u16* wqt  = ws + (size_t)(12u << 20);        // 1M each x4, contiguous
    u16* wkt  = wqt + (1u << 20);
    u16* wvt  = wkt + (1u << 20);
    u16* wot  = wvt + (1u << 20);
    u16* xb   = ws + (size_t)(16u << 20);        // 4M (x in bf16)
    u16* aout = xb;                              // alias: xb dead after qkv_gemm

    prep<<<dim3(16, 16, 20), 256, 0, stream>>>(x, xb, Wq, Wk, Wv, Wo, wqt, wkt, wvt, wot);
    qkv_gemm<<<dim3(16, 64), 256, 0, stream>>>(xb, wqt, bq, bk, bv, qws, kws, vws);
    attn_kernel<<<dim3(32, 32), 256, 0, stream>>>(qws, kws, vws, aout);
    out_gemm<<<dim3(16, 32), 256, 0, stream>>>(aout, wot, bo, out);
}

// Round 17
// 189.621 us; speedup vs baseline: 1.0447x; 1.0447x over previous
//
#include <hip/hip_runtime.h>

typedef unsigned short u16;
typedef __bf16 bf16_t;
typedef bf16_t bf16x8 __attribute__((ext_vector_type(8)));
typedef float f32x4 __attribute__((ext_vector_type(4)));
typedef float f32x16 __attribute__((ext_vector_type(16)));
typedef u16 u16x8 __attribute__((ext_vector_type(8)));
typedef u16 u16x4 __attribute__((ext_vector_type(4)));

#define DEV static __device__ __forceinline__

// ---- constants ----
#define BATCH 2
#define SEQ 2048
#define DM 1024
#define NH 16
#define DH 64
#define NTOK 4096            // BATCH*SEQ
#define ATT_SCALE 0.125f     // 1/sqrt(64)

DEV float bf2f(u16 x) { union { unsigned u; float f; } v; v.u = ((unsigned)x) << 16; return v.f; }
DEV u16 f2bf(float x) {
    union { float f; unsigned u; } v; v.f = x;
    unsigned u = v.u;
    return (u16)((u + 0x7fffu + ((u >> 16) & 1u)) >> 16);
}
DEV f32x4 mfma16(bf16x8 a, bf16x8 b, f32x4 c) {
    return __builtin_amdgcn_mfma_f32_16x16x32_bf16(a, b, c, 0, 0, 0);
}
DEV f32x16 mfma32(bf16x8 a, bf16x8 b, f32x16 c) {
    return __builtin_amdgcn_mfma_f32_32x32x16_bf16(a, b, c, 0, 0, 0);
}
DEV f32x4 zero4() { f32x4 z; z[0] = 0.f; z[1] = 0.f; z[2] = 0.f; z[3] = 0.f; return z; }
DEV f32x16 zero16() {
    f32x16 z;
    #pragma unroll
    for (int i = 0; i < 16; i++) z[i] = 0.f;
    return z;
}

// async global->LDS, 16B per lane.  LDS dest is wave-uniform base + lane*16.
DEV void gl16(const u16* g, u16* l) {
    __builtin_amdgcn_global_load_lds(
        (const __attribute__((address_space(1))) unsigned int*)g,
        (__attribute__((address_space(3))) unsigned int*)l,
        16, 0, 0);
}

// =====================================================================
// Kernel 0: PREP — fused weight transpose (z<4) + x fp32->bf16 (z>=4).
// cvt: 8 floats/thread (2x f32x4 = 32B/lane, coalescing sweet spot).
// grid (16, 16, 12), block 256.
// =====================================================================
__global__ __launch_bounds__(256) void prep(
    const float* __restrict__ x, u16* __restrict__ xb,
    const float* __restrict__ W0, const float* __restrict__ W1,
    const float* __restrict__ W2, const float* __restrict__ W3,
    u16* __restrict__ T0, u16* __restrict__ T1,
    u16* __restrict__ T2, u16* __restrict__ T3)
{
    __shared__ u16 tile[64][65];
    const int z = blockIdx.z;
    const int tid = threadIdx.x;

    if (z >= 4) {
        int bid = (z - 4) * 256 + blockIdx.y * 16 + blockIdx.x;
        int i = (bid * 256 + tid) * 8;
        f32x4 v0 = *(const f32x4*)(x + i);
        f32x4 v1 = *(const f32x4*)(x + i + 4);
        u16x8 o;
        #pragma unroll
        for (int j = 0; j < 4; j++) { o[j] = f2bf(v0[j]); o[4 + j] = f2bf(v1[j]); }
        *(u16x8*)(xb + i) = o;
        return;
    }

    const float* W; u16* T;
    switch (z) {
        case 0:  W = W0; T = T0; break;
        case 1:  W = W1; T = T1; break;
        case 2:  W = W2; T = T2; break;
        default: W = W3; T = T3; break;
    }
    const int o0 = blockIdx.x * 64;
    const int k0 = blockIdx.y * 64;
    #pragma unroll
    for (int v = 0; v < 4; v++) {
        int idx = (tid + v * 256) * 4;
        int r = idx >> 6, c = idx & 63;           // r: k offset, c: o offset
        f32x4 d = *(const f32x4*)(W + (size_t)(k0 + r) * DM + o0 + c);
        #pragma unroll
        for (int j = 0; j < 4; j++) tile[r][c + j] = f2bf(d[j]);
    }
    __syncthreads();
    #pragma unroll
    for (int v = 0; v < 2; v++) {
        int idx = (tid + v * 256) * 8;
        int r = idx >> 6, c = idx & 63;           // r: o offset, c: k offset
        u16x8 d;
        #pragma unroll
        for (int j = 0; j < 8; j++) d[j] = tile[c + j][r];
        *(u16x8*)(T + (size_t)(o0 + r) * DM + k0 + c) = d;
    }
}

// =====================================================================
// Kernel 2: FUSED QKV projection (R14 form — best measured).
// One block = 128 t-rows x 64 o-cols for ALL THREE matrices (A-tile
// staged once, a-fragments reused 3x; t=64 variant REGRESSED: doubling
// t-blocks doubles total B-staging traffic).  XCD swizzle on o-tile.
// grid (16, 32) = 512 blocks, block 256.
// =====================================================================
__global__ __launch_bounds__(256) void qkv_gemm(
    const u16* __restrict__ X, const u16* __restrict__ WT0,
    const float* __restrict__ bq, const float* __restrict__ bk, const float* __restrict__ bv,
    u16* __restrict__ qws, u16* __restrict__ kws, u16* __restrict__ vws)
{
    __shared__ __attribute__((aligned(16))) u16 smem[20480];  // 40 KB
    u16* As = smem;           // 128x64
    u16* Bs = smem + 8192;    // 3 x (64x64)

    const int n  = blockIdx.x + 16 * blockIdx.y;        // 0..511, XCD = n%8
    const int ot = (n & 7) | (((n >> 8) & 1) << 3);     // o-tile 0..15
    const int tt = (n >> 3) & 31;                       // t-tile 0..31
    const int o0 = ot * 64;
    const int t0 = tt * 128;
    const int tid  = threadIdx.x;
    const int wave = tid >> 6;
    const int lane = tid & 63;
    const int q = lane >> 4;
    const int c = lane & 15;
    const int wm = wave >> 1, wn = wave & 1;

    // staging lane constants: row_off = lane>>3, swizzled global chunk
    const int cswz = (((lane & 7) ^ ((lane >> 3) & 7)) * 8);
    const u16* gA = X + (size_t)(t0 + wave * 32 + (lane >> 3)) * DM + cswz;
    const u16* gB = WT0 + (size_t)(o0 + wave * 16 + (lane >> 3)) * DM + cswz;

    f32x4 acc[3][4][2];
    #pragma unroll
    for (int m = 0; m < 3; m++)
        #pragma unroll
        for (int mt = 0; mt < 4; mt++)
            #pragma unroll
            for (int nt = 0; nt < 2; nt++) acc[m][mt][nt] = zero4();

    for (int kt = 0; kt < DM / 64; kt++) {
        __syncthreads();
        #pragma unroll
        for (int i = 0; i < 4; i++)
            gl16(gA + (size_t)i * 8 * DM + kt * 64, As + (wave * 4 + i) * 512);
        #pragma unroll
        for (int m = 0; m < 3; m++)
            #pragma unroll
            for (int i = 0; i < 2; i++)
                gl16(gB + (size_t)m * (1u << 20) + (size_t)i * 8 * DM + kt * 64,
                     Bs + m * 4096 + (wave * 2 + i) * 512);
        __syncthreads();
        #pragma unroll
        for (int ks = 0; ks < 2; ks++) {
            const int cc = ((ks * 4 + q) ^ (c & 7)) * 8;
            bf16x8 a[4];
            #pragma unroll
            for (int mt = 0; mt < 4; mt++)
                a[mt] = *(const bf16x8*)&As[(wm * 64 + mt * 16 + c) * 64 + cc];
            #pragma unroll
            for (int m = 0; m < 3; m++) {
                bf16x8 b[2];
                #pragma unroll
                for (int nt = 0; nt < 2; nt++)
                    b[nt] = *(const bf16x8*)&Bs[m * 4096 + (wn * 32 + nt * 16 + c) * 64 + cc];
                #pragma unroll
                for (int mt = 0; mt < 4; mt++)
                    #pragma unroll
                    for (int nt = 0; nt < 2; nt++)
                        acc[m][mt][nt] = mfma16(a[mt], b[nt], acc[m][mt][nt]);
            }
        }
    }

    // ---- Q, K epilogue: direct scatter to (b,h,s,dh) ----
    #pragma unroll
    for (int m = 0; m < 2; m++) {
        u16* dst = (m == 0) ? qws : kws;
        const float* bias = (m == 0) ? bq : bk;
        #pragma unroll
        for (int mt = 0; mt < 4; mt++)
            #pragma unroll
            for (int nt = 0; nt < 2; nt++)
                #pragma unroll
                for (int r = 0; r < 4; r++) {
                    int mm = wm * 64 + mt * 16 + q * 4 + r;
                    int n2 = wn * 32 + nt * 16 + c;
                    int t = t0 + mm, o = o0 + n2;
                    float val = acc[m][mt][nt][r] + bias[o];
                    int b  = t >> 11, s = t & 2047;
                    int h  = o >> 6,  dh = o & 63;
                    dst[(((size_t)(b * NH + h)) * SEQ + s) * DH + dh] = f2bf(val);
                }
    }

    // ---- V epilogue: transpose through LDS -> coalesced (b,h,dh,s) ----
    __syncthreads();                       // As/Bs reads complete
    #pragma unroll
    for (int mt = 0; mt < 4; mt++)
        #pragma unroll
        for (int nt = 0; nt < 2; nt++) {
            int n_l = wn * 32 + nt * 16 + c;
            int m_l = wm * 64 + mt * 16 + q * 4;
            float bi = bv[o0 + n_l];
            u16x4 pk;
            #pragma unroll
            for (int r = 0; r < 4; r++) pk[r] = f2bf(acc[2][mt][nt][r] + bi);
            *(u16x4*)&smem[n_l * 136 + m_l] = pk;
        }
    __syncthreads();
    const int h = o0 >> 6;                 // one head per 64-wide n-tile
    #pragma unroll
    for (int j = 0; j < 4; j++) {
        int o_l   = (tid >> 4) + j * 16;   // 0..63  (dh)
        int chunk = tid & 15;              // 0..15
        int t_l   = chunk * 8;
        u16x8 d = *(const u16x8*)&smem[o_l * 136 + t_l];
        int t = t0 + t_l;
        int b = t >> 11, s = t & 2047;
        *(u16x8*)&vws[(((size_t)(b * NH + h)) * DH + o_l) * SEQ + s] = d;
    }
}

// =====================================================================
// Kernel 3: flash attention (R14 form — best measured, 52.2us steady).
// 32x32 swapped-QK^T, register-resident P, SPLIT-K + LDS staging +
// XCD head binding + padded LDS via 9x gl16 ([64][72], zero-conflict).
// Block = 64 q-rows, 4 waves (qg,kg); wave (qg,kg): q-rows qg*32..,
// key tiles 2*it+kg.  Partial O,l combined through LDS at the end.
// grid (32,32) = 1024 blocks = 4 blocks/CU.
// =====================================================================
__global__ __launch_bounds__(256, 4) void attn_kernel(
    const u16* __restrict__ qws, const u16* __restrict__ kws,
    const u16* __restrict__ vws, u16* __restrict__ aout)
{
    // u16 units: K tiles [2][64][72] at [0,9216); V tiles at [9216,18432)
    // epilogue alias: Ox [128][36] f32 + Lp[64] + Linv[64] (18.9 KB)
    __shared__ __attribute__((aligned(16))) u16 smem[18432];

    const int n   = blockIdx.x + 32 * blockIdx.y;   // launch id, XCD = n%8
    const int qt  = (n >> 3) & 31;
    const int bh  = (n & 7) | ((n >> 8) << 3);
    const int tid  = threadIdx.x;
    const int wave = tid >> 6;
    const int lane = tid & 63;
    const int c32 = lane & 31;
    const int hi  = lane >> 5;
    const int qg  = wave >> 1;         // q-group (0,1)
    const int kg  = wave & 1;          // key-half (0,1)

    const u16* Qh  = qws + (size_t)bh * SEQ * DH;
    const u16* Kh  = kws + (size_t)bh * SEQ * DH;
    const u16* Vth = vws + (size_t)bh * DH * SEQ;

    const int s0 = qt * 64 + qg * 32;  // wave's q rows

    // ---- staging role: wave stages one [64][72] tile with 9 gl16 ----
    const bool isK = (wave < 2);
    const int  sg  = wave & 1;
    u16* dstT = smem + (isK ? 0 : 9216) + sg * 4608;
    const u16* baseT = isK ? (Kh + (size_t)sg * 64 * DH) : (Vth + sg * 64);
    const size_t itStride = isK ? (size_t)(128 * DH) : (size_t)128;
    int toff[9];
    #pragma unroll
    for (int k = 0; k < 9; k++) {
        int p = 64 * k + lane;          // 16-B position in [0,576)
        int row = p / 9;
        int slot = p - 9 * row;
        int cs = (slot == 8) ? 0 : slot * 8;   // pad slot: duplicate slot 0
        toff[k] = isK ? (row * DH + cs) : (row * SEQ + cs);
    }

    // compute-side buffers (own key-half), padded stride 72
    const u16* KSg = smem + kg * 4608;
    const u16* VSg = smem + 9216 + kg * 4608;

    // Q^T B-fragments: lane holds Q[s0+c32][st*16 + hi*8 + j], pre-scaled
    bf16x8 qf[4];
    #pragma unroll
    for (int st = 0; st < 4; st++) {
        u16x8 raw = *(const u16x8*)(Qh + (size_t)(s0 + c32) * DH + st * 16 + hi * 8);
        u16x8 sv;
        #pragma unroll
        for (int j = 0; j < 8; j++) sv[j] = f2bf(bf2f(raw[j]) * ATT_SCALE);
        qf[st] = *(bf16x8*)&sv;
    }

    float lacc = 0.f;
    f32x16 o_acc[2];
    o_acc[0] = zero16();
    o_acc[1] = zero16();

    for (int it = 0; it < 16; ++it) {
        // stage this iteration's tile (keys [it*128, it*128+128))
        const u16* sb = baseT + (size_t)it * itStride;
        #pragma unroll
        for (int k = 0; k < 9; k++)
            gl16(sb + toff[k], dstT + k * 512);
        __syncthreads();   // vmcnt drained by compiler before barrier

        // S^T = K @ Q^T for own tile; exp+pack per 32-key block.
        // d[kb][s][i]: keys kb*32 + 8s + 4hi + 2i + {0,1}, qrow = c32
        unsigned d[2][4][2];
        #pragma unroll
        for (int kb = 0; kb < 2; kb++) {
            f32x16 sta = zero16();
            #pragma unroll
            for (int st = 0; st < 4; st++) {
                bf16x8 kfv = *(const bf16x8*)&KSg[(kb * 32 + c32) * 72
                                                  + (st * 2 + hi) * 8];
                sta = mfma32(kfv, qf[st], sta);
            }
            #pragma unroll
            for (int s = 0; s < 4; s++) {
                float p0 = __expf(sta[4 * s + 0]);
                float p1 = __expf(sta[4 * s + 1]);
                float p2 = __expf(sta[4 * s + 2]);
                float p3 = __expf(sta[4 * s + 3]);
                lacc += (p0 + p1) + (p2 + p3);
                asm("v_cvt_pk_bf16_f32 %0, %1, %2" : "=v"(d[kb][s][0]) : "v"(p0), "v"(p1));
                asm("v_cvt_pk_bf16_f32 %0, %1, %2" : "=v"(d[kb][s][1]) : "v"(p2), "v"(p3));
            }
        }

        // O += P @ V.  permlane32_swap on the d-pair gives pf =
        // {a0,a1,b0,b1} for ALL lanes directly (no cndmask).
        #pragma unroll
        for (int stv = 0; stv < 4; stv++) {
            const int kb = stv >> 1;
            const int m2 = (stv & 1) * 2;
            unsigned a0 = d[kb][m2][0],     a1 = d[kb][m2][1];
            unsigned b0 = d[kb][m2 + 1][0], b1 = d[kb][m2 + 1][1];
            asm("v_permlane32_swap_b32 %0, %1" : "+v"(a0), "+v"(b0));
            asm("v_permlane32_swap_b32 %0, %1" : "+v"(a1), "+v"(b1));
            union { unsigned u[4]; bf16x8 v; } pf;
            pf.u[0] = a0; pf.u[1] = a1; pf.u[2] = b0; pf.u[3] = b1;
            #pragma unroll
            for (int dhb = 0; dhb < 2; dhb++) {
                bf16x8 vf = *(const bf16x8*)&VSg[(dhb * 32 + c32) * 72
                                                 + (stv * 2 + hi) * 8];
                o_acc[dhb] = mfma32(pf.v, vf, o_acc[dhb]);
            }
        }
        __syncthreads();   // all waves done reading before next staging
    }

    // ---- split-K combine through LDS ----
    float lt = lacc;
    lt += __shfl_xor(lt, 32, 64);

    float* Ox   = (float*)smem;            // [128][36] (stride 36: 2-way free)
    float* Lp   = (float*)smem + 4608;     // [64]
    float* Linv = (float*)smem + 4672;     // [64]

    if (kg == 1) {
        const int xr = qg * 64 + lane;
        #pragma unroll
        for (int dhb = 0; dhb < 2; dhb++)
            #pragma unroll
            for (int s = 0; s < 4; s++) {
                f32x4 t;
                t[0] = o_acc[dhb][s * 4 + 0]; t[1] = o_acc[dhb][s * 4 + 1];
                t[2] = o_acc[dhb][s * 4 + 2]; t[3] = o_acc[dhb][s * 4 + 3];
                *(f32x4*)&Ox[xr * 36 + dhb * 16 + s * 4] = t;
            }
        if (hi == 0) Lp[qg * 32 + c32] = lt;
    }
    __syncthreads();
    if (kg == 0) {
        float inv = 1.0f / (lt + Lp[qg * 32 + c32]);
        if (hi == 0) Linv[qg * 32 + c32] = inv;
    }
    __syncthreads();
    if (kg == 0) {
        const int xr = qg * 64 + lane;
        #pragma unroll
        for (int dhb = 0; dhb < 2; dhb++)
            #pragma unroll
            for (int s = 0; s < 4; s++) {
                f32x4 pp = *(const f32x4*)&Ox[xr * 36 + dhb * 16 + s * 4];
                #pragma unroll
                for (int r = 0; r < 4; r++) o_acc[dhb][s * 4 + r] += pp[r];
            }
        const int b = bh >> 4, h = bh & 15;
        #pragma unroll
        for (int s = 0; s < 4; s++) {
            f32x4 iv = *(const f32x4*)&Linv[qg * 32 + s * 8 + hi * 4];
            #pragma unroll
            for (int r = 0; r < 4; r++) {
                int srow = s0 + s * 8 + hi * 4 + r;   // row = (reg&3)+8(reg>>2)+4hi
                size_t t = (size_t)b * SEQ + srow;
                #pragma unroll
                for (int dhb = 0; dhb < 2; dhb++) {
                    int ch = h * DH + dhb * 32 + c32;
                    aout[t * DM + ch] = f2bf(o_acc[dhb][s * 4 + r] * iv[r]);
                }
            }
        }
    }
}

// =====================================================================
// Kernel 4: output projection, 128x64 tile, fp32 output + XCD swizzle.
// grid (16, 32) = 512 blocks, block 256.
// =====================================================================
__global__ __launch_bounds__(256, 4) void out_gemm(
    const u16* __restrict__ A,  const u16* __restrict__ WT,
    const float* __restrict__ bias, float* __restrict__ out)
{
    __shared__ __attribute__((aligned(16))) u16 smem[12288];
    u16* As = smem;
    u16* Bs = smem + 8192;

    const int n  = blockIdx.x + 16 * blockIdx.y;        // 0..511, XCD = n%8
    const int ot = (n & 7) | (((n >> 8) & 1) << 3);     // o-tile 0..15
    const int tt = (n >> 3) & 31;                       // t-tile 0..31
    const int o0 = ot * 64;
    const int t0 = tt * 128;
    const int tid  = threadIdx.x;
    const int wave = tid >> 6;
    const int lane = tid & 63;
    const int q = lane >> 4;
    const int c = lane & 15;
    const int wm = wave >> 1, wn = wave & 1;

    const int cswz = (((lane & 7) ^ ((lane >> 3) & 7)) * 8);
    const u16* gA = A  + (size_t)(t0 + wave * 32 + (lane >> 3)) * DM + cswz;
    const u16* gB = WT + (size_t)(o0 + wave * 16 + (lane >> 3)) * DM + cswz;

    f32x4 acc[4][2];
    #pragma unroll
    for (int mt = 0; mt < 4; mt++)
        #pragma unroll
        for (int nt = 0; nt < 2; nt++) acc[mt][nt] = zero4();

    for (int kt = 0; kt < DM / 64; kt++) {
        __syncthreads();
        #pragma unroll
        for (int i = 0; i < 4; i++)
            gl16(gA + (size_t)i * 8 * DM + kt * 64, As + (wave * 4 + i) * 512);
        #pragma unroll
        for (int i = 0; i < 2; i++)
            gl16(gB + (size_t)i * 8 * DM + kt * 64, Bs + (wave * 2 + i) * 512);
        __syncthreads();
        #pragma unroll
        for (int ks = 0; ks < 2; ks++) {
            const int cc = ((ks * 4 + q) ^ (c & 7)) * 8;
            bf16x8 a[4], b[2];
            #pragma unroll
            for (int mt = 0; mt < 4; mt++)
                a[mt] = *(const bf16x8*)&As[(wm * 64 + mt * 16 + c) * 64 + cc];
            #pragma unroll
            for (int nt = 0; nt < 2; nt++)
                b[nt] = *(const bf16x8*)&Bs[(wn * 32 + nt * 16 + c) * 64 + cc];
            #pragma unroll
            for (int mt = 0; mt < 4; mt++)
                #pragma unroll
                for (int nt = 0; nt < 2; nt++)
                    acc[mt][nt] = mfma16(a[mt], b[nt], acc[mt][nt]);
        }
    }

    #pragma unroll
    for (int mt = 0; mt < 4; mt++)
        #pragma unroll
        for (int nt = 0; nt < 2; nt++)
            #pragma unroll
            for (int r = 0; r < 4; r++) {
                int m = wm * 64 + mt * 16 + q * 4 + r;
                int n2 = wn * 32 + nt * 16 + c;
                size_t t = t0 + m;
                int o = o0 + n2;
                out[t * DM + o] = acc[mt][nt][r] + bias[o];
            }
}

// =====================================================================
extern "C" void kernel_launch(void* const* d_in, const int* in_sizes, int n_in,
                              void* d_out, int out_size, void* d_ws, size_t ws_size,
                              hipStream_t stream)
{
    const float* x  = (const float*)d_in[0];
    const float* Wq = (const float*)d_in[1];
    const float* bq = (const float*)d_in[2];
    const float* Wk = (const float*)d_in[3];
    const float* bk = (const float*)d_in[4];
    const float* Wv = (const float*)d_in[5];
    const float* bv = (const float*)d_in[6];
    const float* Wo = (const float*)d_in[7];
    const float* bo = (const float*)d_in[8];
    float* out = (float*)d_out;

    // workspace carve (bf16 elements): 20M elems = 40 MB
    u16* ws   = (u16*)d_ws;
    u16* qws  = ws;                              // 4M elems
    u16* kws  = ws + (size_t)(4u << 20);         // 4M
    u16* vws  = ws + (size_t)(8u << 20);         // 4M (transposed per-head)
    u16* wqt  = ws + (size_t)(12u << 20);        // 1M each x4, contiguous
    u16* wkt  = wqt + (1u << 20);
    u16* wvt  = wkt + (1u << 20);
    u16* wot  = wvt + (1u << 20);
    u16* xb   = ws + (size_t)(16u << 20);        // 4M (x in bf16)
    u16* aout = xb;                              // alias: xb dead after qkv_gemm

    prep<<<dim3(16, 16, 12), 256, 0, stream>>>(x, xb, Wq, Wk, Wv, Wo, wqt, wkt, wvt, wot);
    qkv_gemm<<<dim3(16, 32), 256, 0, stream>>>(xb, wqt, bq, bk, bv, qws, kws, vws);
    attn_kernel<<<dim3(32, 32), 256, 0, stream>>>(qws, kws, vws, aout);
    out_gemm<<<dim3(16, 32), 256, 0, stream>>>(aout, wot, bo, out);
}

// Round 18
// 182.912 us; speedup vs baseline: 1.0830x; 1.0367x over previous
//
#include <hip/hip_runtime.h>

typedef unsigned short u16;
typedef __bf16 bf16_t;
typedef bf16_t bf16x8 __attribute__((ext_vector_type(8)));
typedef float f32x4 __attribute__((ext_vector_type(4)));
typedef float f32x16 __attribute__((ext_vector_type(16)));
typedef u16 u16x8 __attribute__((ext_vector_type(8)));
typedef u16 u16x4 __attribute__((ext_vector_type(4)));

#define DEV static __device__ __forceinline__

// ---- constants ----
#define BATCH 2
#define SEQ 2048
#define DM 1024
#define NH 16
#define DH 64
#define NTOK 4096            // BATCH*SEQ
#define ATT_SCALE 0.125f     // 1/sqrt(64)

DEV float bf2f(u16 x) { union { unsigned u; float f; } v; v.u = ((unsigned)x) << 16; return v.f; }
DEV u16 f2bf(float x) {
    union { float f; unsigned u; } v; v.f = x;
    unsigned u = v.u;
    return (u16)((u + 0x7fffu + ((u >> 16) & 1u)) >> 16);
}
DEV f32x4 mfma16(bf16x8 a, bf16x8 b, f32x4 c) {
    return __builtin_amdgcn_mfma_f32_16x16x32_bf16(a, b, c, 0, 0, 0);
}
DEV f32x16 mfma32(bf16x8 a, bf16x8 b, f32x16 c) {
    return __builtin_amdgcn_mfma_f32_32x32x16_bf16(a, b, c, 0, 0, 0);
}
DEV f32x4 zero4() { f32x4 z; z[0] = 0.f; z[1] = 0.f; z[2] = 0.f; z[3] = 0.f; return z; }
DEV f32x16 zero16() {
    f32x16 z;
    #pragma unroll
    for (int i = 0; i < 16; i++) z[i] = 0.f;
    return z;
}

// async global->LDS, 16B per lane.  LDS dest is wave-uniform base + lane*16.
DEV void gl16(const u16* g, u16* l) {
    __builtin_amdgcn_global_load_lds(
        (const __attribute__((address_space(1))) unsigned int*)g,
        (__attribute__((address_space(3))) unsigned int*)l,
        16, 0, 0);
}

// =====================================================================
// Kernel 0: PREP — fused weight transpose (z<4) + x fp32->bf16 (z>=4).
// grid (16, 16, 20), block 256.
// =====================================================================
__global__ __launch_bounds__(256) void prep(
    const float* __restrict__ x, u16* __restrict__ xb,
    const float* __restrict__ W0, const float* __restrict__ W1,
    const float* __restrict__ W2, const float* __restrict__ W3,
    u16* __restrict__ T0, u16* __restrict__ T1,
    u16* __restrict__ T2, u16* __restrict__ T3)
{
    __shared__ u16 tile[64][65];
    const int z = blockIdx.z;
    const int tid = threadIdx.x;

    if (z >= 4) {
        int bid = (z - 4) * 256 + blockIdx.y * 16 + blockIdx.x;
        int i = (bid * 256 + tid) * 4;
        f32x4 v = *(const f32x4*)(x + i);
        u16x4 o;
        #pragma unroll
        for (int j = 0; j < 4; j++) o[j] = f2bf(v[j]);
        *(u16x4*)(xb + i) = o;
        return;
    }

    const float* W; u16* T;
    switch (z) {
        case 0:  W = W0; T = T0; break;
        case 1:  W = W1; T = T1; break;
        case 2:  W = W2; T = T2; break;
        default: W = W3; T = T3; break;
    }
    const int o0 = blockIdx.x * 64;
    const int k0 = blockIdx.y * 64;
    #pragma unroll
    for (int v = 0; v < 4; v++) {
        int idx = (tid + v * 256) * 4;
        int r = idx >> 6, c = idx & 63;           // r: k offset, c: o offset
        f32x4 d = *(const f32x4*)(W + (size_t)(k0 + r) * DM + o0 + c);
        #pragma unroll
        for (int j = 0; j < 4; j++) tile[r][c + j] = f2bf(d[j]);
    }
    __syncthreads();
    #pragma unroll
    for (int v = 0; v < 2; v++) {
        int idx = (tid + v * 256) * 8;
        int r = idx >> 6, c = idx & 63;           // r: o offset, c: k offset
        u16x8 d;
        #pragma unroll
        for (int j = 0; j < 8; j++) d[j] = tile[c + j][r];
        *(u16x8*)(T + (size_t)(o0 + r) * DM + k0 + c) = d;
    }
}

// =====================================================================
// Kernel 2: FUSED QKV projection.  One block = 128 t-rows x 64 o-cols
// for ALL THREE matrices (A-tile staged once, a-fragments reused 3x).
// grid (16 o-tiles, 32 t-tiles), block 256.
// =====================================================================
__global__ __launch_bounds__(256) void qkv_gemm(
    const u16* __restrict__ X, const u16* __restrict__ WT0,
    const float* __restrict__ bq, const float* __restrict__ bk, const float* __restrict__ bv,
    u16* __restrict__ qws, u16* __restrict__ kws, u16* __restrict__ vws)
{
    __shared__ __attribute__((aligned(16))) u16 smem[20480];  // 40 KB
    u16* As = smem;           // 128x64
    u16* Bs = smem + 8192;    // 3 x (64x64)

    const int o0 = blockIdx.x * 64;
    const int t0 = blockIdx.y * 128;
    const int tid  = threadIdx.x;
    const int wave = tid >> 6;
    const int lane = tid & 63;
    const int q = lane >> 4;
    const int c = lane & 15;
    const int wm = wave >> 1, wn = wave & 1;

    // staging lane constants: row_off = lane>>3, swizzled global chunk
    const int cswz = (((lane & 7) ^ ((lane >> 3) & 7)) * 8);
    const u16* gA = X + (size_t)(t0 + wave * 32 + (lane >> 3)) * DM + cswz;
    const u16* gB = WT0 + (size_t)(o0 + wave * 16 + (lane >> 3)) * DM + cswz;

    f32x4 acc[3][4][2];
    #pragma unroll
    for (int m = 0; m < 3; m++)
        #pragma unroll
        for (int mt = 0; mt < 4; mt++)
            #pragma unroll
            for (int nt = 0; nt < 2; nt++) acc[m][mt][nt] = zero4();

    for (int kt = 0; kt < DM / 64; kt++) {
        __syncthreads();
        #pragma unroll
        for (int i = 0; i < 4; i++)
            gl16(gA + (size_t)i * 8 * DM + kt * 64, As + (wave * 4 + i) * 512);
        #pragma unroll
        for (int m = 0; m < 3; m++)
            #pragma unroll
            for (int i = 0; i < 2; i++)
                gl16(gB + (size_t)m * (1u << 20) + (size_t)i * 8 * DM + kt * 64,
                     Bs + m * 4096 + (wave * 2 + i) * 512);
        __syncthreads();
        #pragma unroll
        for (int ks = 0; ks < 2; ks++) {
            const int cc = ((ks * 4 + q) ^ (c & 7)) * 8;
            bf16x8 a[4];
            #pragma unroll
            for (int mt = 0; mt < 4; mt++)
                a[mt] = *(const bf16x8*)&As[(wm * 64 + mt * 16 + c) * 64 + cc];
            #pragma unroll
            for (int m = 0; m < 3; m++) {
                bf16x8 b[2];
                #pragma unroll
                for (int nt = 0; nt < 2; nt++)
                    b[nt] = *(const bf16x8*)&Bs[m * 4096 + (wn * 32 + nt * 16 + c) * 64 + cc];
                #pragma unroll
                for (int mt = 0; mt < 4; mt++)
                    #pragma unroll
                    for (int nt = 0; nt < 2; nt++)
                        acc[m][mt][nt] = mfma16(a[mt], b[nt], acc[m][mt][nt]);
            }
        }
    }

    // ---- Q, K epilogue: direct scatter to (b,h,s,dh) ----
    #pragma unroll
    for (int m = 0; m < 2; m++) {
        u16* dst = (m == 0) ? qws : kws;
        const float* bias = (m == 0) ? bq : bk;
        #pragma unroll
        for (int mt = 0; mt < 4; mt++)
            #pragma unroll
            for (int nt = 0; nt < 2; nt++)
                #pragma unroll
                for (int r = 0; r < 4; r++) {
                    int mm = wm * 64 + mt * 16 + q * 4 + r;
                    int n  = wn * 32 + nt * 16 + c;
                    int t = t0 + mm, o = o0 + n;
                    float val = acc[m][mt][nt][r] + bias[o];
                    int b  = t >> 11, s = t & 2047;
                    int h  = o >> 6,  dh = o & 63;
                    dst[(((size_t)(b * NH + h)) * SEQ + s) * DH + dh] = f2bf(val);
                }
    }

    // ---- V epilogue: transpose through LDS -> coalesced (b,h,dh,s) ----
    __syncthreads();                       // As/Bs reads complete
    #pragma unroll
    for (int mt = 0; mt < 4; mt++)
        #pragma unroll
        for (int nt = 0; nt < 2; nt++) {
            int n_l = wn * 32 + nt * 16 + c;
            int m_l = wm * 64 + mt * 16 + q * 4;
            float bi = bv[o0 + n_l];
            u16x4 pk;
            #pragma unroll
            for (int r = 0; r < 4; r++) pk[r] = f2bf(acc[2][mt][nt][r] + bi);
            *(u16x4*)&smem[n_l * 136 + m_l] = pk;
        }
    __syncthreads();
    const int h = o0 >> 6;                 // one head per 64-wide n-tile
    #pragma unroll
    for (int j = 0; j < 4; j++) {
        int o_l   = (tid >> 4) + j * 16;   // 0..63  (dh)
        int chunk = tid & 15;              // 0..15
        int t_l   = chunk * 8;
        u16x8 d = *(const u16x8*)&smem[o_l * 136 + t_l];
        int t = t0 + t_l;
        int b = t >> 11, s = t & 2047;
        *(u16x8*)&vws[(((size_t)(b * NH + h)) * DH + o_l) * SEQ + s] = d;
    }
}

// =====================================================================
// Kernel 3: flash attention — 32x32 swapped-QK^T, register-resident P.
// 8-WAVE (512-thread) block: 128 q-rows, waves (qg in 0..3, kg in 0..1)
// SHARE the double-buffered K/V tiles -> 73.7KB LDS serves 8 waves:
// 2 blocks/CU = 16 waves/CU = 4 waves/SIMD.  Grid (16,32) = 512 blocks,
// all resident, single round.  launch_bounds (512, 2): VGPR cap 128.
// Counted vmcnt + raw s_barrier pipeline (T4), padded LDS via 9x gl16
// (zero conflict), XCD head binding (head bh on XCD bh%8, L2-resident).
// Staging: waves 0-3 each stage one of the 4 tiles; waves 4-7 skip.
// Partial O,l combined through LDS at the end (split-K over kg).
// =====================================================================
__global__ __launch_bounds__(512, 2) void attn_kernel(
    const u16* __restrict__ qws, const u16* __restrict__ kws,
    const u16* __restrict__ vws, u16* __restrict__ aout)
{
    // u16 units: K tiles [(buf*2+kg)*4608] at [0,18432);
    //            V tiles at [18432, 36864).  73,728 B total.
    // epilogue alias: Ox [256][36] f32 + Lp[128] + Linv[128] (37.9 KB)
    __shared__ __attribute__((aligned(16))) u16 smem[36864];

    const int n   = blockIdx.x + 16 * blockIdx.y;   // launch id, XCD = n%8
    const int qt  = (n >> 3) & 15;
    const int bh  = (n & 7) | ((n >> 7) << 3);
    const int tid  = threadIdx.x;
    const int wave = tid >> 6;
    const int lane = tid & 63;
    const int c32 = lane & 31;
    const int hi  = lane >> 5;
    const int qg  = wave >> 1;         // q-group (0..3)
    const int kg  = wave & 1;          // key-half (0,1)

    const u16* Qh  = qws + (size_t)bh * SEQ * DH;
    const u16* Kh  = kws + (size_t)bh * SEQ * DH;
    const u16* Vth = vws + (size_t)bh * DH * SEQ;

    const int s0 = qt * 128 + qg * 32; // wave's q rows

    // ---- staging role: waves 0-3 stage one [64][72] tile with 9 gl16 ----
    const bool isK = (wave < 2);
    const int  sg  = wave & 1;
    u16* dstB = smem + (isK ? 0 : 18432) + sg * 4608;   // + buf*9216
    const u16* baseT = isK ? (Kh + (size_t)sg * 64 * DH) : (Vth + sg * 64);
    const size_t itStride = isK ? (size_t)(128 * DH) : (size_t)128;
    int toff[9];
    #pragma unroll
    for (int k = 0; k < 9; k++) {
        int p = 64 * k + lane;          // 16-B position in [0,576)
        int row = p / 9;
        int slot = p - 9 * row;
        int cs = (slot == 8) ? 0 : slot * 8;   // pad slot: duplicate slot 0
        toff[k] = isK ? (row * DH + cs) : (row * SEQ + cs);
    }

    // compute-side buffers (own key-half), padded stride 72
    const u16* KS0 = smem + kg * 4608;
    const u16* KS1 = smem + 9216 + kg * 4608;
    const u16* VS0 = smem + 18432 + kg * 4608;
    const u16* VS1 = smem + 18432 + 9216 + kg * 4608;

    // Q^T B-fragments: lane holds Q[s0+c32][st*16 + hi*8 + j], pre-scaled
    bf16x8 qf[4];
    #pragma unroll
    for (int st = 0; st < 4; st++) {
        u16x8 raw = *(const u16x8*)(Qh + (size_t)(s0 + c32) * DH + st * 16 + hi * 8);
        u16x8 sv;
        #pragma unroll
        for (int j = 0; j < 8; j++) sv[j] = f2bf(bf2f(raw[j]) * ATT_SCALE);
        qf[st] = *(bf16x8*)&sv;
    }

    float lacc = 0.f;
    f32x16 o_acc[2];
    o_acc[0] = zero16();
    o_acc[1] = zero16();

#define STAGE(BUF, IT) do {                                              \
        if (wave < 4) {                                                  \
            const u16* sb_ = baseT + (size_t)(IT) * itStride;            \
            u16* dd_ = dstB + (BUF) * 9216;                              \
            _Pragma("unroll")                                            \
            for (int k_ = 0; k_ < 9; k_++)                               \
                gl16(sb_ + toff[k_], dd_ + k_ * 512);                    \
        }                                                                \
    } while (0)

#define VMW9 asm volatile("s_waitcnt vmcnt(9)" ::: "memory")
#define VMW0 asm volatile("s_waitcnt vmcnt(0)" ::: "memory")
#define BAR  __builtin_amdgcn_s_barrier()
#define SB0  __builtin_amdgcn_sched_barrier(0)

#define COMPUTE(KSg, VSg) do {                                           \
        unsigned d[2][4][2];                                             \
        _Pragma("unroll")                                                \
        for (int kb = 0; kb < 2; kb++) {                                 \
            f32x16 sta = zero16();                                       \
            _Pragma("unroll")                                            \
            for (int st = 0; st < 4; st++) {                             \
                bf16x8 kfv = *(const bf16x8*)&(KSg)[(kb * 32 + c32) * 72 \
                                                    + (st * 2 + hi) * 8];\
                sta = mfma32(kfv, qf[st], sta);                          \
            }                                                            \
            _Pragma("unroll")                                            \
            for (int s = 0; s < 4; s++) {                                \
                float p0 = __expf(sta[4 * s + 0]);                       \
                float p1 = __expf(sta[4 * s + 1]);                       \
                float p2 = __expf(sta[4 * s + 2]);                       \
                float p3 = __expf(sta[4 * s + 3]);                       \
                lacc += (p0 + p1) + (p2 + p3);                           \
                asm("v_cvt_pk_bf16_f32 %0, %1, %2"                       \
                    : "=v"(d[kb][s][0]) : "v"(p0), "v"(p1));             \
                asm("v_cvt_pk_bf16_f32 %0, %1, %2"                       \
                    : "=v"(d[kb][s][1]) : "v"(p2), "v"(p3));             \
            }                                                            \
        }                                                                \
        _Pragma("unroll")                                                \
        for (int stv = 0; stv < 4; stv++) {                              \
            const int kb = stv >> 1;                                     \
            const int m2 = (stv & 1) * 2;                                \
            unsigned a0 = d[kb][m2][0],     a1 = d[kb][m2][1];           \
            unsigned b0 = d[kb][m2 + 1][0], b1 = d[kb][m2 + 1][1];       \
            asm("v_permlane32_swap_b32 %0, %1" : "+v"(a0), "+v"(b0));    \
            asm("v_permlane32_swap_b32 %0, %1" : "+v"(a1), "+v"(b1));    \
            union { unsigned u[4]; bf16x8 v; } pf;                       \
            pf.u[0] = a0; pf.u[1] = a1; pf.u[2] = b0; pf.u[3] = b1;      \
            _Pragma("unroll")                                            \
            for (int dhb = 0; dhb < 2; dhb++) {                          \
                bf16x8 vf = *(const bf16x8*)&(VSg)[(dhb * 32 + c32) * 72 \
                                                   + (stv * 2 + hi) * 8];\
                o_acc[dhb] = mfma32(pf.v, vf, o_acc[dhb]);               \
            }                                                            \
        }                                                                \
    } while (0)

    // prologue: stage tile 0 into buf 0
    STAGE(0, 0);

    for (int it = 0; it < 16; it += 2) {
        // ---- tile it (buf 0) ----
        STAGE(1, it + 1);          // it+1 <= 15 always
        VMW9;                      // buf0 writes landed; buf1's 9 in flight
        BAR; SB0;                  // publish buf0 (prev COMPUTE's reads done)
        COMPUTE(KS0, VS0);
        BAR;                       // all waves done reading buf0
        // ---- tile it+1 (buf 1) ----
        if (it + 2 < 16) { STAGE(0, it + 2); VMW9; }
        else             { VMW0; }
        BAR; SB0;                  // publish buf1
        COMPUTE(KS1, VS1);
        BAR;                       // all waves done reading buf1
    }
#undef STAGE
#undef COMPUTE
#undef VMW9
#undef VMW0
#undef BAR
#undef SB0

    // ---- split-K combine through LDS ----
    float lt = lacc;
    lt += __shfl_xor(lt, 32, 64);

    float* Ox   = (float*)smem;            // [256][36] (stride 36: 2-way free)
    float* Lp   = (float*)smem + 9216;     // [128]
    float* Linv = (float*)smem + 9344;     // [128]

    if (kg == 1) {
        const int xr = qg * 64 + lane;
        #pragma unroll
        for (int dhb = 0; dhb < 2; dhb++)
            #pragma unroll
            for (int s = 0; s < 4; s++) {
                f32x4 t;
                t[0] = o_acc[dhb][s * 4 + 0]; t[1] = o_acc[dhb][s * 4 + 1];
                t[2] = o_acc[dhb][s * 4 + 2]; t[3] = o_acc[dhb][s * 4 + 3];
                *(f32x4*)&Ox[xr * 36 + dhb * 16 + s * 4] = t;
            }
        if (hi == 0) Lp[qg * 32 + c32] = lt;
    }
    __syncthreads();
    if (kg == 0) {
        float inv = 1.0f / (lt + Lp[qg * 32 + c32]);
        if (hi == 0) Linv[qg * 32 + c32] = inv;
    }
    __syncthreads();
    if (kg == 0) {
        const int xr = qg * 64 + lane;
        #pragma unroll
        for (int dhb = 0; dhb < 2; dhb++)
            #pragma unroll
            for (int s = 0; s < 4; s++) {
                f32x4 pp = *(const f32x4*)&Ox[xr * 36 + dhb * 16 + s * 4];
                #pragma unroll
                for (int r = 0; r < 4; r++) o_acc[dhb][s * 4 + r] += pp[r];
            }
        const int b = bh >> 4, h = bh & 15;
        #pragma unroll
        for (int s = 0; s < 4; s++) {
            f32x4 iv = *(const f32x4*)&Linv[qg * 32 + s * 8 + hi * 4];
            #pragma unroll
            for (int r = 0; r < 4; r++) {
                int srow = s0 + s * 8 + hi * 4 + r;   // row = (reg&3)+8(reg>>2)+4hi
                size_t t = (size_t)b * SEQ + srow;
                #pragma unroll
                for (int dhb = 0; dhb < 2; dhb++) {
                    int ch = h * DH + dhb * 32 + c32;
                    aout[t * DM + ch] = f2bf(o_acc[dhb][s * 4 + r] * iv[r]);
                }
            }
        }
    }
}

// =====================================================================
// Kernel 4: output projection, 128x64 tile, fp32 output.
// grid (16 n-tiles, 32 m-tiles), block 256.
// =====================================================================
__global__ __launch_bounds__(256, 4) void out_gemm(
    const u16* __restrict__ A,  const u16* __restrict__ WT,
    const float* __restrict__ bias, float* __restrict__ out)
{
    __shared__ __attribute__((aligned(16))) u16 smem[12288];
    u16* As = smem;
    u16* Bs = smem + 8192;

    const int o0 = blockIdx.x * 64;
    const int t0 = blockIdx.y * 128;
    const int tid  = threadIdx.x;
    const int wave = tid >> 6;
    const int lane = tid & 63;
    const int q = lane >> 4;
    const int c = lane & 15;
    const int wm = wave >> 1, wn = wave & 1;

    const int cswz = (((lane & 7) ^ ((lane >> 3) & 7)) * 8);
    const u16* gA = A  + (size_t)(t0 + wave * 32 + (lane >> 3)) * DM + cswz;
    const u16* gB = WT + (size_t)(o0 + wave * 16 + (lane >> 3)) * DM + cswz;

    f32x4 acc[4][2];
    #pragma unroll
    for (int mt = 0; mt < 4; mt++)
        #pragma unroll
        for (int nt = 0; nt < 2; nt++) acc[mt][nt] = zero4();

    for (int kt = 0; kt < DM / 64; kt++) {
        __syncthreads();
        #pragma unroll
        for (int i = 0; i < 4; i++)
            gl16(gA + (size_t)i * 8 * DM + kt * 64, As + (wave * 4 + i) * 512);
        #pragma unroll
        for (int i = 0; i < 2; i++)
            gl16(gB + (size_t)i * 8 * DM + kt * 64, Bs + (wave * 2 + i) * 512);
        __syncthreads();
        #pragma unroll
        for (int ks = 0; ks < 2; ks++) {
            const int cc = ((ks * 4 + q) ^ (c & 7)) * 8;
            bf16x8 a[4], b[2];
            #pragma unroll
            for (int mt = 0; mt < 4; mt++)
                a[mt] = *(const bf16x8*)&As[(wm * 64 + mt * 16 + c) * 64 + cc];
            #pragma unroll
            for (int nt = 0; nt < 2; nt++)
                b[nt] = *(const bf16x8*)&Bs[(wn * 32 + nt * 16 + c) * 64 + cc];
            #pragma unroll
            for (int mt = 0; mt < 4; mt++)
                #pragma unroll
                for (int nt = 0; nt < 2; nt++)
                    acc[mt][nt] = mfma16(a[mt], b[nt], acc[mt][nt]);
        }
    }

    #pragma unroll
    for (int mt = 0; mt < 4; mt++)
        #pragma unroll
        for (int nt = 0; nt < 2; nt++)
            #pragma unroll
            for (int r = 0; r < 4; r++) {
                int m = wm * 64 + mt * 16 + q * 4 + r;
                int n = wn * 32 + nt * 16 + c;
                size_t t = t0 + m;
                int o = o0 + n;
                out[t * DM + o] = acc[mt][nt][r] + bias[o];
            }
}

// =====================================================================
extern "C" void kernel_launch(void* const* d_in, const int* in_sizes, int n_in,
                              void* d_out, int out_size, void* d_ws, size_t ws_size,
                              hipStream_t stream)
{
    const float* x  = (const float*)d_in[0];
    const float* Wq = (const float*)d_in[1];
    const float* bq = (const float*)d_in[2];
    const float* Wk = (const float*)d_in[3];
    const float* bk = (const float*)d_in[4];
    const float* Wv = (const float*)d_in[5];
    const float* bv = (const float*)d_in[6];
    const float* Wo = (const float*)d_in[7];
    const float* bo = (const float*)d_in[8];
    float* out = (float*)d_out;

    // workspace carve (bf16 elements): 20M elems = 40 MB
    u16* ws   = (u16*)d_ws;
    u16* qws  = ws;                              // 4M elems
    u16* kws  = ws + (size_t)(4u << 20);         // 4M
    u16* vws  = ws + (size_t)(8u << 20);         // 4M (transposed per-head)
    u16* wqt  = ws + (size_t)(12u << 20);        // 1M each x4, contiguous
    u16* wkt  = wqt + (1u << 20);
    u16* wvt  = wkt + (1u << 20);
    u16* wot  = wvt + (1u << 20);
    u16* xb   = ws + (size_t)(16u << 20);        // 4M (x in bf16)
    u16* aout = xb;                              // alias: xb dead after qkv_gemm

    prep<<<dim3(16, 16, 20), 256, 0, stream>>>(x, xb, Wq, Wk, Wv, Wo, wqt, wkt, wvt, wot);
    qkv_gemm<<<dim3(16, 32), 256, 0, stream>>>(xb, wqt, bq, bk, bv, qws, kws, vws);
    attn_kernel<<<dim3(16, 32), 512, 0, stream>>>(qws, kws, vws, aout);
    out_gemm<<<dim3(16, 32), 256, 0, stream>>>(aout, wot, bo, out);
}